// Round 1
// baseline (1632.206 us; speedup 1.0000x reference)
//
#include <hip/hip_runtime.h>
#include <math.h>

#define NB 8
#define LK 4096
#define LQ 4096
#define DD 512
#define LSEL 2744
#define LPAD 2752

typedef __attribute__((ext_vector_type(8))) short bf16x8;
typedef __attribute__((ext_vector_type(4))) float f32x4;

__device__ __forceinline__ unsigned short f2bf(float x) {
  unsigned u = __float_as_uint(x);
  unsigned r = (u + 0x7fffu + ((u >> 16) & 1u)) >> 16;
  return (unsigned short)r;
}

__device__ __forceinline__ unsigned fkey(float x) {
  unsigned b = __float_as_uint(x);
  return (b & 0x80000000u) ? ~b : (b | 0x80000000u);
}

// keys f32 [B][LK][D] -> keysT f32 [B][D][LK]
__global__ void k_transpose(const float* __restrict__ keys, float* __restrict__ keysT) {
  __shared__ float tile[32][33];
  int b = blockIdx.z;
  int k0 = blockIdx.x * 32, d0 = blockIdx.y * 32;
  int tx = threadIdx.x, ty = threadIdx.y;
  const float* src = keys + ((size_t)b * LK + k0) * DD + d0;
#pragma unroll
  for (int i = 0; i < 4; i++) tile[ty + 8 * i][tx] = src[(size_t)(ty + 8 * i) * DD + tx];
  __syncthreads();
  float* dst = keysT + ((size_t)b * DD + d0) * LK + k0;
#pragma unroll
  for (int i = 0; i < 4; i++) dst[(size_t)(ty + 8 * i) * LK + tx] = tile[tx][ty + 8 * i];
}

// elementwise f32 -> bf16
__global__ void k_cast(const float4* __restrict__ in, ushort4* __restrict__ out, int n4) {
  int i = blockIdx.x * 256 + threadIdx.x;
  if (i >= n4) return;
  float4 v = in[i];
  ushort4 o;
  o.x = f2bf(v.x); o.y = f2bf(v.y); o.z = f2bf(v.z); o.w = f2bf(v.w);
  out[i] = o;
}

// values f32 [B][LK][D] -> chunk-tiled bf16 VT [B][LK/8][D][8keys]
__global__ void k_vt(const float* __restrict__ values, unsigned short* __restrict__ vt) {
  __shared__ float tile[32][65];
  int b = blockIdx.z, k0 = blockIdx.x * 32, d0 = blockIdx.y * 64;
  int tid = threadIdx.x;
  const float* src = values + ((size_t)b * LK + k0) * DD + d0;
#pragma unroll
  for (int j = 0; j < 8; j++) {
    int li = tid + 256 * j;
    tile[li >> 6][li & 63] = src[(size_t)(li >> 6) * DD + (li & 63)];
  }
  __syncthreads();
  int c = tid >> 6, d = tid & 63;
  union { unsigned short us[8]; uint4 v; } pk;
#pragma unroll
  for (int j = 0; j < 8; j++) pk.us[j] = f2bf(tile[c * 8 + j][d]);
  size_t ci = ((size_t)b * (LK / 8) + (size_t)(k0 >> 3) + c) * DD + d0 + d;
  ((uint4*)vt)[ci] = pk.v;
}

// per-(b,d): mean of top-LSEL of keysT row, exact radix select
__global__ __launch_bounds__(256) void k_kreduce(const float* __restrict__ keysT, float* __restrict__ kred) {
  __shared__ float vals[4096];
  __shared__ unsigned hist[16];
  __shared__ double redd[256];
  __shared__ unsigned redu[256];
  int row = blockIdx.x;
  int tid = threadIdx.x;
  const float* src = keysT + (size_t)row * LK;
  for (int i = tid; i < LK; i += 256) vals[i] = src[i];
  __syncthreads();
  unsigned prefix = 0;
  int rank = LSEL;
  for (int shift = 28; shift >= 0; shift -= 4) {
    if (tid < 16) hist[tid] = 0;
    __syncthreads();
    unsigned cnt[16];
#pragma unroll
    for (int j = 0; j < 16; j++) cnt[j] = 0;
    for (int i = tid; i < LK; i += 256) {
      unsigned u = fkey(vals[i]);
      bool cand = (shift == 28) || ((u >> (shift + 4)) == prefix);
      if (cand) cnt[(u >> shift) & 15]++;
    }
#pragma unroll
    for (int j = 0; j < 16; j++) if (cnt[j]) atomicAdd(&hist[j], cnt[j]);
    __syncthreads();
    int r = rank;
    unsigned bin = 15;
    for (;;) {
      int c = (int)hist[bin];
      if (c >= r) break;
      r -= c;
      if (bin == 0) break;
      bin--;
    }
    prefix = (prefix << 4) | bin;
    rank = r;
    __syncthreads();
  }
  double fsum = 0.0;
  unsigned fcnt = 0;
  for (int i = tid; i < LK; i += 256) {
    unsigned u = fkey(vals[i]);
    if (u > prefix) { fsum += (double)vals[i]; fcnt++; }
  }
  redd[tid] = fsum; redu[tid] = fcnt;
  __syncthreads();
  for (int s = 128; s > 0; s >>= 1) {
    if (tid < s) { redd[tid] += redd[tid + s]; redu[tid] += redu[tid + s]; }
    __syncthreads();
  }
  if (tid == 0) {
    unsigned u = prefix;
    unsigned bits = (u & 0x80000000u) ? (u ^ 0x80000000u) : ~u;
    float tval = __uint_as_float(bits);
    kred[row] = (float)((redd[0] + (double)(LSEL - (int)redu[0]) * (double)tval) / (double)LSEL);
  }
}

// sqk[b][q] = dot(K_reduce[b], queries[b][q]) with f64 accumulation
__global__ __launch_bounds__(256) void k_sqk(const float* __restrict__ queries, const float* __restrict__ kred,
                                             float* __restrict__ sqk) {
  int gw = blockIdx.x * 4 + (threadIdx.x >> 6);
  int lane = threadIdx.x & 63;
  int b = gw >> 12;
  const float* qp = queries + (size_t)gw * DD;
  const float* kp = kred + (size_t)b * DD;
  float4 a0 = ((const float4*)qp)[lane * 2];
  float4 a1 = ((const float4*)qp)[lane * 2 + 1];
  float4 c0 = ((const float4*)kp)[lane * 2];
  float4 c1 = ((const float4*)kp)[lane * 2 + 1];
  double s = (double)a0.x * c0.x + (double)a0.y * c0.y + (double)a0.z * c0.z + (double)a0.w * c0.w +
             (double)a1.x * c1.x + (double)a1.y * c1.y + (double)a1.z * c1.z + (double)a1.w * c1.w;
#pragma unroll
  for (int m = 1; m < 64; m <<= 1) s += __shfl_xor(s, m);
  if (lane == 0) sqk[gw] = (float)s;
}

// per-batch: exact top-LSEL selection (ties by lowest index), deterministic scan compaction
__global__ __launch_bounds__(512) void k_select(const float* __restrict__ sqk, int* __restrict__ qidx) {
  __shared__ float vals[4096];
  __shared__ unsigned hist[16];
  __shared__ unsigned wsum[8];
  int b = blockIdx.x, tid = threadIdx.x;
  const float* src = sqk + (size_t)b * LQ;
  for (int i = tid; i < LQ; i += 512) vals[i] = src[i];
  __syncthreads();
  unsigned prefix = 0;
  int rank = LSEL;
  for (int shift = 28; shift >= 0; shift -= 4) {
    if (tid < 16) hist[tid] = 0;
    __syncthreads();
    unsigned cnt[16];
#pragma unroll
    for (int j = 0; j < 16; j++) cnt[j] = 0;
    for (int i = tid; i < LQ; i += 512) {
      unsigned u = fkey(vals[i]);
      bool cand = (shift == 28) || ((u >> (shift + 4)) == prefix);
      if (cand) cnt[(u >> shift) & 15]++;
    }
#pragma unroll
    for (int j = 0; j < 16; j++) if (cnt[j]) atomicAdd(&hist[j], cnt[j]);
    __syncthreads();
    int r = rank;
    unsigned bin = 15;
    for (;;) {
      int c = (int)hist[bin];
      if (c >= r) break;
      r -= c;
      if (bin == 0) break;
      bin--;
    }
    prefix = (prefix << 4) | bin;
    rank = r;
    __syncthreads();
  }
  unsigned gt = 0, eq = 0;
#pragma unroll
  for (int j = 0; j < 8; j++) {
    int i = tid * 8 + j;
    unsigned u = fkey(vals[i]);
    gt += (u > prefix) ? 1u : 0u;
    eq += (u == prefix) ? 1u : 0u;
  }
  unsigned packed = (gt << 16) | eq;
  unsigned x = packed;
  int lane = tid & 63, wv = tid >> 6;
#pragma unroll
  for (int off2 = 1; off2 < 64; off2 <<= 1) {
    unsigned t = __shfl_up(x, off2);
    if (lane >= off2) x += t;
  }
  if (lane == 63) wsum[wv] = x;
  __syncthreads();
  unsigned wpre = 0, total = 0;
#pragma unroll
  for (int i = 0; i < 8; i++) {
    unsigned v = wsum[i];
    if (i < wv) wpre += v;
    total += v;
  }
  unsigned exclv = x + wpre - packed;
  unsigned total_gt = total >> 16;
  unsigned need_eq = (unsigned)LSEL - total_gt;
  unsigned gpos = exclv >> 16;
  unsigned epos = exclv & 0xffffu;
  for (int j = 0; j < 8; j++) {
    int i = tid * 8 + j;
    unsigned u = fkey(vals[i]);
    if (u > prefix) {
      qidx[(size_t)b * LPAD + gpos] = i;
      gpos++;
    } else if (u == prefix) {
      if (epos < need_eq) qidx[(size_t)b * LPAD + total_gt + epos] = i;
      epos++;
    }
  }
  for (int p = LSEL + tid; p < LPAD; p += 512) qidx[(size_t)b * LPAD + p] = -1;
}

// gather selected queries -> bf16 [B][LPAD][D] (pad rows zero)
__global__ void k_gather(const float* __restrict__ queries, const int* __restrict__ qidx,
                         unsigned short* __restrict__ qs) {
  int r = blockIdx.x, b = blockIdx.y;
  int tid = threadIdx.x;
  int q = qidx[(size_t)b * LPAD + r];
  ushort4* dst = (ushort4*)(qs + ((size_t)b * LPAD + r) * DD);
  if (q < 0) {
    ushort4 z; z.x = 0; z.y = 0; z.z = 0; z.w = 0;
    dst[tid] = z;
  } else {
    const float4* srcv = (const float4*)(queries + ((size_t)b * LQ + q) * DD);
    float4 v = srcv[tid];
    ushort4 o;
    o.x = f2bf(v.x); o.y = f2bf(v.y); o.z = f2bf(v.z); o.w = f2bf(v.w);
    dst[tid] = o;
  }
}

__global__ void k_meanv_part(const float* __restrict__ values, float* __restrict__ part) {
  int d = blockIdx.x * 256 + threadIdx.x;
  int ks = blockIdx.y, b = blockIdx.z;
  const float* src = values + ((size_t)b * LK + (size_t)ks * 256) * DD + d;
  float s = 0.f;
  for (int k = 0; k < 256; k++) s += src[(size_t)k * DD];
  part[((size_t)b * 16 + ks) * DD + d] = s;
}

__global__ void k_meanv_fin(const float* __restrict__ part, float* __restrict__ meanv) {
  int d = blockIdx.x * 256 + threadIdx.x;
  int b = blockIdx.y;
  float s = 0.f;
#pragma unroll
  for (int i = 0; i < 16; i++) s += part[((size_t)b * 16 + i) * DD + d];
  meanv[(size_t)b * DD + d] = s * (1.0f / 4096.0f);
}

__global__ void k_fill(float4* __restrict__ out4, const float4* __restrict__ mv4) {
  int i = blockIdx.x * 256 + threadIdx.x;
  int row = i >> 7;
  int b = row >> 12;
  int d4 = i & 127;
  out4[i] = mv4[b * 128 + d4];
}

// flash attention: Q-tile 64 (4 waves x 16q, full D per wave), K-tile 32
__global__ __launch_bounds__(256, 2) void k_attn(const unsigned short* __restrict__ qs,
                                                 const unsigned short* __restrict__ kbf,
                                                 const unsigned short* __restrict__ vt,
                                                 const int* __restrict__ qidx,
                                                 float* __restrict__ out) {
  __shared__ unsigned char smem[65536];
  unsigned short* Kl = (unsigned short*)smem;            // [32 rows][512] (1KB rows, XOR chunk swizzle)
  unsigned short* Vl = (unsigned short*)(smem + 32768);  // chunk-major [4][512][8]
  int b = blockIdx.y;
  int q0 = blockIdx.x * 64;
  int tid = threadIdx.x;
  int w = tid >> 6, lane = tid & 63;
  int l15 = lane & 15, l4 = lane >> 4;
  unsigned short* Pl = (unsigned short*)smem + w * 512;  // aliases K rows 0..3, used only post-QK

  const unsigned short* qrow = qs + ((size_t)b * LPAD + q0 + w * 16 + l15) * DD;
  bf16x8 qf[16];
#pragma unroll
  for (int t = 0; t < 16; t++) qf[t] = *(const bf16x8*)(qrow + t * 32 + l4 * 8);

  f32x4 O[32];
#pragma unroll
  for (int i = 0; i < 32; i++) O[i] = (f32x4){0.f, 0.f, 0.f, 0.f};
  float m_run[4], l_run[4];
#pragma unroll
  for (int r = 0; r < 4; r++) { m_run[r] = -INFINITY; l_run[r] = 0.f; }

  const float SCALE = 0.04419417418f;  // 1/sqrt(512)

  const uint4* gK = (const uint4*)(kbf + (size_t)b * LK * DD);
  const uint4* gV = (const uint4*)vt;
  uint4* lK = (uint4*)Kl;
  uint4* lV = (uint4*)Vl;

  for (int kt = 0; kt < LK / 32; kt++) {
    // stage K rows (row-major, XOR-swizzled chunks within 128B groups)
#pragma unroll
    for (int rr = 0; rr < 8; rr++) {
      int k = w * 8 + rr;
      uint4 tmpv = gK[(size_t)(kt * 32 + k) * 64 + lane];
      lK[k * 64 + (lane ^ (k & 7))] = tmpv;
    }
    // stage VT chunk-tile (linear)
#pragma unroll
    for (int rr = 0; rr < 8; rr++) {
      int li = w * 8 + rr;
      int c = li >> 3, ii = li & 7;
      size_t ci = ((size_t)b * 512 + (size_t)kt * 4 + c) * DD + ii * 64 + lane;
      uint4 tmpv = gV[ci];
      lV[c * 512 + ii * 64 + lane] = tmpv;
    }
    __syncthreads();

    // QK^T: S[16q x 32k] per wave, full-D contraction
    f32x4 accS0 = (f32x4){0.f, 0.f, 0.f, 0.f};
    f32x4 accS1 = (f32x4){0.f, 0.f, 0.f, 0.f};
#pragma unroll
    for (int t = 0; t < 16; t++) {
      int cc = t * 4 + l4;
      int k0r = l15;
      bf16x8 bk0 = *(const bf16x8*)(Kl + (size_t)k0r * 512 + ((cc ^ (k0r & 7)) * 8));
      accS0 = __builtin_amdgcn_mfma_f32_16x16x32_bf16(qf[t], bk0, accS0, 0, 0, 0);
      int k1r = 16 + l15;
      bf16x8 bk1 = *(const bf16x8*)(Kl + (size_t)k1r * 512 + ((cc ^ (k1r & 7)) * 8));
      accS1 = __builtin_amdgcn_mfma_f32_16x16x32_bf16(qf[t], bk1, accS1, 0, 0, 0);
    }
    __syncthreads();  // all QK reads of K done before P overwrites K rows 0..3

    // online softmax (rows = l4*4+r, keys spread over l&15)
    float sf[4], p0a[4], p1a[4];
#pragma unroll
    for (int r = 0; r < 4; r++) {
      float s0 = accS0[r] * SCALE, s1 = accS1[r] * SCALE;
      float mx = fmaxf(s0, s1);
      mx = fmaxf(mx, __shfl_xor(mx, 1));
      mx = fmaxf(mx, __shfl_xor(mx, 2));
      mx = fmaxf(mx, __shfl_xor(mx, 4));
      mx = fmaxf(mx, __shfl_xor(mx, 8));
      float mn = fmaxf(m_run[r], mx);
      float f = __expf(m_run[r] - mn);
      float p0 = __expf(s0 - mn), p1 = __expf(s1 - mn);
      float rs = p0 + p1;
      rs += __shfl_xor(rs, 1);
      rs += __shfl_xor(rs, 2);
      rs += __shfl_xor(rs, 4);
      rs += __shfl_xor(rs, 8);
      m_run[r] = mn;
      l_run[r] = l_run[r] * f + rs;
      sf[r] = f;
      p0a[r] = p0;
      p1a[r] = p1;
    }
    // write P bf16 (per-wave region, XOR slot swizzle)
#pragma unroll
    for (int r = 0; r < 4; r++) {
      int row = l4 * 4 + r;
      int sw = (row >> 1) & 3;
      int key0 = l15;
      Pl[row * 32 + (((key0 >> 3) ^ sw) * 8) + (key0 & 7)] = f2bf(p0a[r]);
      int key1 = 16 + l15;
      Pl[row * 32 + (((key1 >> 3) ^ sw) * 8) + (key1 & 7)] = f2bf(p1a[r]);
    }
    // rescale O
#pragma unroll
    for (int nt = 0; nt < 32; nt++) {
#pragma unroll
      for (int r = 0; r < 4; r++) O[nt][r] *= sf[r];
    }
    __syncthreads();

    // PV: O[16q x 512d] += P[16x32] * V[32x512]
    bf16x8 aP = *(const bf16x8*)(Pl + l15 * 32 + ((l4 ^ ((l15 >> 1) & 3)) * 8));
#pragma unroll
    for (int nt = 0; nt < 32; nt++) {
      bf16x8 bv = *(const bf16x8*)(Vl + ((size_t)l4 * 512 + nt * 16 + l15) * 8);
      O[nt] = __builtin_amdgcn_mfma_f32_16x16x32_bf16(aP, bv, O[nt], 0, 0, 0);
    }
    __syncthreads();  // everyone done before next staging
  }

  // epilogue: divide by l and scatter to output rows
#pragma unroll
  for (int r = 0; r < 4; r++) {
    int qp = q0 + w * 16 + l4 * 4 + r;
    int qg = qidx[(size_t)b * LPAD + qp];
    if (qg >= 0) {
      float inv = 1.0f / l_run[r];
      float* orow = out + ((size_t)b * LQ + qg) * DD;
#pragma unroll
      for (int nt = 0; nt < 32; nt++) orow[nt * 16 + l15] = O[nt][r] * inv;
    }
  }
}

extern "C" void kernel_launch(void* const* d_in, const int* in_sizes, int n_in,
                              void* d_out, int out_size, void* d_ws, size_t ws_size,
                              hipStream_t stream) {
  const float* queries = (const float*)d_in[0];
  const float* keys = (const float*)d_in[1];
  const float* values = (const float*)d_in[2];
  float* out = (float*)d_out;
  char* ws = (char*)d_ws;
  size_t off = 0;
  float* keysT = (float*)(ws + off); off += (size_t)NB * DD * LK * 4;                 // 64 MB
  unsigned short* kbf = (unsigned short*)(ws + off); off += (size_t)NB * LK * DD * 2; // 32 MB
  unsigned short* vt = (unsigned short*)(ws + off); off += (size_t)NB * LK * DD * 2;  // 32 MB
  unsigned short* qs = (unsigned short*)(ws + off); off += (size_t)NB * LPAD * DD * 2;
  float* kred = (float*)(ws + off); off += (size_t)NB * DD * 4;
  float* sqkv = (float*)(ws + off); off += (size_t)NB * LQ * 4;
  int* qidx = (int*)(ws + off); off += (size_t)NB * LPAD * 4;
  float* part = (float*)(ws + off); off += (size_t)NB * 16 * DD * 4;
  float* meanv = (float*)(ws + off); off += (size_t)NB * DD * 4;

  k_transpose<<<dim3(LK / 32, DD / 32, NB), dim3(32, 8), 0, stream>>>(keys, keysT);
  k_cast<<<(NB * LK * DD / 4 + 255) / 256, 256, 0, stream>>>((const float4*)keys, (ushort4*)kbf,
                                                             NB * LK * DD / 4);
  k_vt<<<dim3(LK / 32, DD / 64, NB), 256, 0, stream>>>(values, vt);
  k_kreduce<<<NB * DD, 256, 0, stream>>>(keysT, kred);
  k_sqk<<<NB * LQ / 4, 256, 0, stream>>>(queries, kred, sqkv);
  k_select<<<NB, 512, 0, stream>>>(sqkv, qidx);
  k_gather<<<dim3(LPAD, NB), 128, 0, stream>>>(queries, qidx, qs);
  k_meanv_part<<<dim3(DD / 256, 16, NB), 256, 0, stream>>>(values, part);
  k_meanv_fin<<<dim3(DD / 256, NB), 256, 0, stream>>>(part, meanv);
  k_fill<<<NB * LQ * DD / 4 / 256, 256, 0, stream>>>((float4*)out, (const float4*)meanv);
  k_attn<<<dim3(LPAD / 64, NB), 256, 0, stream>>>(qs, kbf, vt, qidx, out);
}

// Round 2
// 912.120 us; speedup vs baseline: 1.7895x; 1.7895x over previous
//
#include <hip/hip_runtime.h>
#include <math.h>

#define NB 8
#define LK 4096
#define LQ 4096
#define DD 512
#define LSEL 2744
#define LPAD 2784   // 29 * 96

typedef __attribute__((ext_vector_type(8))) short bf16x8;
typedef __attribute__((ext_vector_type(4))) float f32x4;

#define AS1 __attribute__((address_space(1)))
#define AS3 __attribute__((address_space(3)))

__device__ __forceinline__ unsigned short f2bf(float x) {
  unsigned u = __float_as_uint(x);
  unsigned r = (u + 0x7fffu + ((u >> 16) & 1u)) >> 16;
  return (unsigned short)r;
}

__device__ __forceinline__ unsigned fkey(float x) {
  unsigned b = __float_as_uint(x);
  return (b & 0x80000000u) ? ~b : (b | 0x80000000u);
}

// keys f32 [B][LK][D] -> keysT f32 [B][D][LK]  (+ fused bf16 cast of keys)
__global__ void k_transpose(const float* __restrict__ keys, float* __restrict__ keysT,
                            unsigned short* __restrict__ kbf) {
  __shared__ float tile[32][33];
  int b = blockIdx.z;
  int k0 = blockIdx.x * 32, d0 = blockIdx.y * 32;
  int tx = threadIdx.x, ty = threadIdx.y;
  const float* src = keys + ((size_t)b * LK + k0) * DD + d0;
#pragma unroll
  for (int i = 0; i < 4; i++) {
    float v = src[(size_t)(ty + 8 * i) * DD + tx];
    tile[ty + 8 * i][tx] = v;
    kbf[((size_t)b * LK + k0 + ty + 8 * i) * DD + d0 + tx] = f2bf(v);
  }
  __syncthreads();
  float* dst = keysT + ((size_t)b * DD + d0) * LK + k0;
#pragma unroll
  for (int i = 0; i < 4; i++) dst[(size_t)(ty + 8 * i) * LK + tx] = tile[tx][ty + 8 * i];
}

// values f32 [B][LK][D] -> chunk-tiled bf16 VT [B][LK/8][D][8keys]  (+ fused mean partials)
__global__ void k_vt(const float* __restrict__ values, unsigned short* __restrict__ vt,
                     float* __restrict__ part) {
  __shared__ float tile[32][65];
  __shared__ float psum[4][64];
  int b = blockIdx.z, k0 = blockIdx.x * 32, d0 = blockIdx.y * 64;
  int tid = threadIdx.x;
  const float* src = values + ((size_t)b * LK + k0) * DD + d0;
#pragma unroll
  for (int j = 0; j < 8; j++) {
    int li = tid + 256 * j;
    tile[li >> 6][li & 63] = src[(size_t)(li >> 6) * DD + (li & 63)];
  }
  __syncthreads();
  int c = tid >> 6, d = tid & 63;
  union { unsigned short us[8]; uint4 v; } pk;
  float fs = 0.f;
#pragma unroll
  for (int j = 0; j < 8; j++) {
    float v = tile[c * 8 + j][d];
    pk.us[j] = f2bf(v);
    fs += v;
  }
  size_t ci = ((size_t)b * (LK / 8) + (size_t)(k0 >> 3) + c) * DD + d0 + d;
  ((uint4*)vt)[ci] = pk.v;
  psum[c][d] = fs;
  __syncthreads();
  if (tid < 64) {
    float s = psum[0][tid] + psum[1][tid] + psum[2][tid] + psum[3][tid];
    part[((size_t)b * 128 + (k0 >> 5)) * DD + d0 + tid] = s;
  }
}

// per-(b,d): mean of top-LSEL of keysT row, exact radix select
__global__ __launch_bounds__(256) void k_kreduce(const float* __restrict__ keysT, float* __restrict__ kred) {
  __shared__ float vals[4096];
  __shared__ unsigned hist[16];
  __shared__ double redd[256];
  __shared__ unsigned redu[256];
  int row = blockIdx.x;
  int tid = threadIdx.x;
  const float* src = keysT + (size_t)row * LK;
  for (int i = tid; i < LK; i += 256) vals[i] = src[i];
  __syncthreads();
  unsigned prefix = 0;
  int rank = LSEL;
  for (int shift = 28; shift >= 0; shift -= 4) {
    if (tid < 16) hist[tid] = 0;
    __syncthreads();
    unsigned cnt[16];
#pragma unroll
    for (int j = 0; j < 16; j++) cnt[j] = 0;
    for (int i = tid; i < LK; i += 256) {
      unsigned u = fkey(vals[i]);
      bool cand = (shift == 28) || ((u >> (shift + 4)) == prefix);
      if (cand) cnt[(u >> shift) & 15]++;
    }
#pragma unroll
    for (int j = 0; j < 16; j++) if (cnt[j]) atomicAdd(&hist[j], cnt[j]);
    __syncthreads();
    int r = rank;
    unsigned bin = 15;
    for (;;) {
      int c = (int)hist[bin];
      if (c >= r) break;
      r -= c;
      if (bin == 0) break;
      bin--;
    }
    prefix = (prefix << 4) | bin;
    rank = r;
    __syncthreads();
  }
  double fsum = 0.0;
  unsigned fcnt = 0;
  for (int i = tid; i < LK; i += 256) {
    unsigned u = fkey(vals[i]);
    if (u > prefix) { fsum += (double)vals[i]; fcnt++; }
  }
  redd[tid] = fsum; redu[tid] = fcnt;
  __syncthreads();
  for (int s = 128; s > 0; s >>= 1) {
    if (tid < s) { redd[tid] += redd[tid + s]; redu[tid] += redu[tid + s]; }
    __syncthreads();
  }
  if (tid == 0) {
    unsigned u = prefix;
    unsigned bits = (u & 0x80000000u) ? (u ^ 0x80000000u) : ~u;
    float tval = __uint_as_float(bits);
    kred[row] = (float)((redd[0] + (double)(LSEL - (int)redu[0]) * (double)tval) / (double)LSEL);
  }
}

// sqk[b][q] = dot(K_reduce[b], queries[b][q]) with f64 accumulation
__global__ __launch_bounds__(256) void k_sqk(const float* __restrict__ queries, const float* __restrict__ kred,
                                             float* __restrict__ sqk) {
  int gw = blockIdx.x * 4 + (threadIdx.x >> 6);
  int lane = threadIdx.x & 63;
  int b = gw >> 12;
  const float* qp = queries + (size_t)gw * DD;
  const float* kp = kred + (size_t)b * DD;
  float4 a0 = ((const float4*)qp)[lane * 2];
  float4 a1 = ((const float4*)qp)[lane * 2 + 1];
  float4 c0 = ((const float4*)kp)[lane * 2];
  float4 c1 = ((const float4*)kp)[lane * 2 + 1];
  double s = (double)a0.x * c0.x + (double)a0.y * c0.y + (double)a0.z * c0.z + (double)a0.w * c0.w +
             (double)a1.x * c1.x + (double)a1.y * c1.y + (double)a1.z * c1.z + (double)a1.w * c1.w;
#pragma unroll
  for (int m = 1; m < 64; m <<= 1) s += __shfl_xor(s, m);
  if (lane == 0) sqk[gw] = (float)s;
}

// per-batch: exact top-LSEL selection (ties by lowest index), deterministic scan compaction
__global__ __launch_bounds__(512) void k_select(const float* __restrict__ sqk, int* __restrict__ qidx) {
  __shared__ float vals[4096];
  __shared__ unsigned hist[16];
  __shared__ unsigned wsum[8];
  int b = blockIdx.x, tid = threadIdx.x;
  const float* src = sqk + (size_t)b * LQ;
  for (int i = tid; i < LQ; i += 512) vals[i] = src[i];
  __syncthreads();
  unsigned prefix = 0;
  int rank = LSEL;
  for (int shift = 28; shift >= 0; shift -= 4) {
    if (tid < 16) hist[tid] = 0;
    __syncthreads();
    unsigned cnt[16];
#pragma unroll
    for (int j = 0; j < 16; j++) cnt[j] = 0;
    for (int i = tid; i < LQ; i += 512) {
      unsigned u = fkey(vals[i]);
      bool cand = (shift == 28) || ((u >> (shift + 4)) == prefix);
      if (cand) cnt[(u >> shift) & 15]++;
    }
#pragma unroll
    for (int j = 0; j < 16; j++) if (cnt[j]) atomicAdd(&hist[j], cnt[j]);
    __syncthreads();
    int r = rank;
    unsigned bin = 15;
    for (;;) {
      int c = (int)hist[bin];
      if (c >= r) break;
      r -= c;
      if (bin == 0) break;
      bin--;
    }
    prefix = (prefix << 4) | bin;
    rank = r;
    __syncthreads();
  }
  unsigned gt = 0, eq = 0;
#pragma unroll
  for (int j = 0; j < 8; j++) {
    int i = tid * 8 + j;
    unsigned u = fkey(vals[i]);
    gt += (u > prefix) ? 1u : 0u;
    eq += (u == prefix) ? 1u : 0u;
  }
  unsigned packed = (gt << 16) | eq;
  unsigned x = packed;
  int lane = tid & 63, wv = tid >> 6;
#pragma unroll
  for (int off2 = 1; off2 < 64; off2 <<= 1) {
    unsigned t = __shfl_up(x, off2);
    if (lane >= off2) x += t;
  }
  if (lane == 63) wsum[wv] = x;
  __syncthreads();
  unsigned wpre = 0, total = 0;
#pragma unroll
  for (int i = 0; i < 8; i++) {
    unsigned v = wsum[i];
    if (i < wv) wpre += v;
    total += v;
  }
  unsigned exclv = x + wpre - packed;
  unsigned total_gt = total >> 16;
  unsigned need_eq = (unsigned)LSEL - total_gt;
  unsigned gpos = exclv >> 16;
  unsigned epos = exclv & 0xffffu;
  for (int j = 0; j < 8; j++) {
    int i = tid * 8 + j;
    unsigned u = fkey(vals[i]);
    if (u > prefix) {
      qidx[(size_t)b * LPAD + gpos] = i;
      gpos++;
    } else if (u == prefix) {
      if (epos < need_eq) qidx[(size_t)b * LPAD + total_gt + epos] = i;
      epos++;
    }
  }
  for (int p = LSEL + tid; p < LPAD; p += 512) qidx[(size_t)b * LPAD + p] = -1;
}

// gather selected queries -> bf16 [B][LPAD][D] (pad rows zero)
__global__ void k_gather(const float* __restrict__ queries, const int* __restrict__ qidx,
                         unsigned short* __restrict__ qs) {
  int r = blockIdx.x, b = blockIdx.y;
  int tid = threadIdx.x;
  int q = qidx[(size_t)b * LPAD + r];
  ushort4* dst = (ushort4*)(qs + ((size_t)b * LPAD + r) * DD);
  if (q < 0) {
    ushort4 z; z.x = 0; z.y = 0; z.z = 0; z.w = 0;
    dst[tid] = z;
  } else {
    const float4* srcv = (const float4*)(queries + ((size_t)b * LQ + q) * DD);
    float4 v = srcv[tid];
    ushort4 o;
    o.x = f2bf(v.x); o.y = f2bf(v.y); o.z = f2bf(v.z); o.w = f2bf(v.w);
    dst[tid] = o;
  }
}

__global__ void k_meanv_fin(const float* __restrict__ part, float* __restrict__ meanv) {
  int d = blockIdx.x * 256 + threadIdx.x;
  int b = blockIdx.y;
  float s = 0.f;
  for (int i = 0; i < 128; i++) s += part[((size_t)b * 128 + i) * DD + d];
  meanv[(size_t)b * DD + d] = s * (1.0f / 4096.0f);
}

__global__ void k_fill(float4* __restrict__ out4, const float4* __restrict__ mv4) {
  int i = blockIdx.x * 256 + threadIdx.x;
  int row = i >> 7;
  int b = row >> 12;
  int d4 = i & 127;
  out4[i] = mv4[b * 128 + d4];
}

// flash attention v2: 6 waves x 16q (Q-tile 96), KVBLK 32, K/V double-buffered via
// global_load_lds (pre-swizzled K source), 1 barrier/iter, per-wave P region, defer-max.
__global__ __launch_bounds__(384, 1) void k_attn(const unsigned short* __restrict__ qs,
                                                 const unsigned short* __restrict__ kbf,
                                                 const unsigned short* __restrict__ vt,
                                                 const int* __restrict__ qidx,
                                                 float* __restrict__ out) {
  extern __shared__ char smem[];
  // layout: K dbuf [2][32768] @0, V dbuf [2][32768] @65536, P [6][1024] @131072
  int b = blockIdx.y;
  int q0 = blockIdx.x * 96;
  int tid = threadIdx.x;
  int w = tid >> 6, lane = tid & 63;
  int l15 = lane & 15, l4 = lane >> 4;
  unsigned short* Pl = (unsigned short*)(smem + 131072 + w * 1024);

  const unsigned short* qrow = qs + ((size_t)b * LPAD + q0 + w * 16 + l15) * DD;
  bf16x8 qf[16];
#pragma unroll
  for (int t = 0; t < 16; t++) qf[t] = *(const bf16x8*)(qrow + t * 32 + l4 * 8);

  f32x4 O[32];
#pragma unroll
  for (int i = 0; i < 32; i++) O[i] = (f32x4){0.f, 0.f, 0.f, 0.f};
  float m_run[4], l_run[4];
#pragma unroll
  for (int r = 0; r < 4; r++) { m_run[r] = -1e30f; l_run[r] = 0.f; }

  const float SCALE = 0.04419417418f;  // 1/sqrt(512)

  const char* gKbase = (const char*)(kbf + (size_t)b * LK * DD);
  const char* gVbase = (const char*)vt;

#define STAGE(KT, BUF)                                                                          \
  do {                                                                                          \
    char* Kd = smem + (size_t)(BUF)*32768;                                                      \
    char* Vd = smem + 65536 + (size_t)(BUF)*32768;                                              \
    for (int u = w; u < 64; u += 6) {                                                           \
      if (u < 32) {                                                                             \
        const char* srcp = gKbase + (size_t)((KT)*32 + u) * 1024 + ((lane ^ (u & 7)) << 4);     \
        __builtin_amdgcn_global_load_lds((const AS1 unsigned int*)(uintptr_t)srcp,              \
                                         (AS3 unsigned int*)(uintptr_t)(Kd + u * 1024), 16, 0,  \
                                         0);                                                    \
      } else {                                                                                  \
        int li = u - 32;                                                                        \
        int c = li >> 3;                                                                        \
        size_t vidx = (((size_t)b * 512 + (size_t)((KT)*4 + c)) * 512 + (li & 7) * 64 + lane);  \
        const char* srcp = gVbase + vidx * 16;                                                  \
        __builtin_amdgcn_global_load_lds((const AS1 unsigned int*)(uintptr_t)srcp,              \
                                         (AS3 unsigned int*)(uintptr_t)(Vd + li * 1024), 16, 0, \
                                         0);                                                    \
      }                                                                                         \
    }                                                                                           \
  } while (0)

  STAGE(0, 0);
  __syncthreads();
  int cur = 0;

  for (int kt = 0; kt < LK / 32; kt++) {
    if (kt + 1 < LK / 32) STAGE(kt + 1, cur ^ 1);

    const unsigned short* Kl = (const unsigned short*)(smem + (size_t)cur * 32768);
    const unsigned short* Vl = (const unsigned short*)(smem + 65536 + (size_t)cur * 32768);

    // QK^T: S[16q x 32k] per wave, full-D contraction
    f32x4 accS0 = (f32x4){0.f, 0.f, 0.f, 0.f};
    f32x4 accS1 = (f32x4){0.f, 0.f, 0.f, 0.f};
#pragma unroll
    for (int t = 0; t < 16; t++) {
      int cc = t * 4 + l4;
      bf16x8 bk0 = *(const bf16x8*)(Kl + (size_t)l15 * 512 + ((cc ^ (l15 & 7)) * 8));
      accS0 = __builtin_amdgcn_mfma_f32_16x16x32_bf16(qf[t], bk0, accS0, 0, 0, 0);
      int k1r = 16 + l15;
      bf16x8 bk1 = *(const bf16x8*)(Kl + (size_t)k1r * 512 + ((cc ^ (k1r & 7)) * 8));
      accS1 = __builtin_amdgcn_mfma_f32_16x16x32_bf16(qf[t], bk1, accS1, 0, 0, 0);
    }

    // online softmax with defer-max (THR=8)
    float s0v[4], s1v[4], mx_[4];
    float need = 0.f;
#pragma unroll
    for (int r = 0; r < 4; r++) {
      float s0 = accS0[r] * SCALE, s1 = accS1[r] * SCALE;
      float mx = fmaxf(s0, s1);
      mx = fmaxf(mx, __shfl_xor(mx, 1));
      mx = fmaxf(mx, __shfl_xor(mx, 2));
      mx = fmaxf(mx, __shfl_xor(mx, 4));
      mx = fmaxf(mx, __shfl_xor(mx, 8));
      mx_[r] = mx;
      need = fmaxf(need, mx - m_run[r]);
      s0v[r] = s0; s1v[r] = s1;
    }
    if (!__all(need <= 8.0f)) {
#pragma unroll
      for (int r = 0; r < 4; r++) {
        float mn = fmaxf(m_run[r], mx_[r]);
        float f = __expf(m_run[r] - mn);
        m_run[r] = mn;
        l_run[r] *= f;
#pragma unroll
        for (int nt = 0; nt < 32; nt++) O[nt][r] *= f;
      }
    }
#pragma unroll
    for (int r = 0; r < 4; r++) {
      float p0 = __expf(s0v[r] - m_run[r]);
      float p1 = __expf(s1v[r] - m_run[r]);
      float rs = p0 + p1;
      rs += __shfl_xor(rs, 1);
      rs += __shfl_xor(rs, 2);
      rs += __shfl_xor(rs, 4);
      rs += __shfl_xor(rs, 8);
      l_run[r] += rs;
      int row = l4 * 4 + r;
      int sw = (row >> 1) & 3;
      Pl[row * 32 + (((l15 >> 3) ^ sw) * 8) + (l15 & 7)] = f2bf(p0);
      int key1 = 16 + l15;
      Pl[row * 32 + (((key1 >> 3) ^ sw) * 8) + (key1 & 7)] = f2bf(p1);
    }

    // PV: O[16q x 512d] += P[16x32] * V[32x512]  (same-wave P, no barrier needed)
    bf16x8 aP = *(const bf16x8*)(Pl + l15 * 32 + ((l4 ^ ((l15 >> 1) & 3)) * 8));
#pragma unroll
    for (int nt = 0; nt < 32; nt++) {
      bf16x8 bv = *(const bf16x8*)(Vl + ((size_t)l4 * 512 + nt * 16 + l15) * 8);
      O[nt] = __builtin_amdgcn_mfma_f32_16x16x32_bf16(aP, bv, O[nt], 0, 0, 0);
    }

    __syncthreads();  // next tile staged (vmcnt drained) + everyone done with cur buffers
    cur ^= 1;
  }

  // epilogue: divide by l and scatter to output rows
#pragma unroll
  for (int r = 0; r < 4; r++) {
    int qp = q0 + w * 16 + l4 * 4 + r;
    int qg = qidx[(size_t)b * LPAD + qp];
    if (qg >= 0) {
      float inv = 1.0f / l_run[r];
      float* orow = out + ((size_t)b * LQ + qg) * DD;
#pragma unroll
      for (int nt = 0; nt < 32; nt++) orow[nt * 16 + l15] = O[nt][r] * inv;
    }
  }
#undef STAGE
}

extern "C" void kernel_launch(void* const* d_in, const int* in_sizes, int n_in,
                              void* d_out, int out_size, void* d_ws, size_t ws_size,
                              hipStream_t stream) {
  const float* queries = (const float*)d_in[0];
  const float* keys = (const float*)d_in[1];
  const float* values = (const float*)d_in[2];
  float* out = (float*)d_out;
  char* ws = (char*)d_ws;
  size_t off = 0;
  float* keysT = (float*)(ws + off); off += (size_t)NB * DD * LK * 4;                 // 64 MB
  unsigned short* kbf = (unsigned short*)(ws + off); off += (size_t)NB * LK * DD * 2; // 32 MB
  unsigned short* vt = (unsigned short*)(ws + off); off += (size_t)NB * LK * DD * 2;  // 32 MB
  float* kred = (float*)(ws + off); off += (size_t)NB * DD * 4;
  float* sqkv = (float*)(ws + off); off += (size_t)NB * LQ * 4;
  int* qidx = (int*)(ws + off); off += (size_t)NB * LPAD * 4;
  float* part = (float*)(ws + off); off += (size_t)NB * 128 * DD * 4;                 // 2 MB
  float* meanv = (float*)(ws + off); off += (size_t)NB * DD * 4;
  // qs aliases keysT's region: keysT is dead after k_kreduce, qs written by k_gather after it
  unsigned short* qs = (unsigned short*)keysT;  // 22.8 MB < 64 MB

  hipFuncSetAttribute((const void*)k_attn, hipFuncAttributeMaxDynamicSharedMemorySize, 137216);

  k_transpose<<<dim3(LK / 32, DD / 32, NB), dim3(32, 8), 0, stream>>>(keys, keysT, kbf);
  k_vt<<<dim3(LK / 32, DD / 64, NB), 256, 0, stream>>>(values, vt, part);
  k_kreduce<<<NB * DD, 256, 0, stream>>>(keysT, kred);
  k_sqk<<<NB * LQ / 4, 256, 0, stream>>>(queries, kred, sqkv);
  k_select<<<NB, 512, 0, stream>>>(sqkv, qidx);
  k_gather<<<dim3(LPAD, NB), 128, 0, stream>>>(queries, qidx, qs);
  k_meanv_fin<<<dim3(DD / 256, NB), 256, 0, stream>>>(part, meanv);
  k_fill<<<NB * LQ * DD / 4 / 256, 256, 0, stream>>>((float4*)out, (const float4*)meanv);
  k_attn<<<dim3(LPAD / 96, NB), 384, 137216, stream>>>(qs, kbf, vt, qidx, out);
}